// Round 1
// 9668.868 us; speedup vs baseline: 1.0645x; 1.0645x over previous
//
#include <hip/hip_runtime.h>
#include <hip/hip_bf16.h>

#define B_    32
#define T_    2048
#define F_    512
#define H_    512
#define NTEAM 8           // one team per XCD (runtime-verified via HW_REG_XCC_ID)
#define NROLE 32          // WGs per team; each role owns 16 h-cols
#define NCOLS 64          // z-cols per WG (4 gates x 16 h-cols)
#define HCW   16          // h-cols per WG
#define WPITCH 520        // LDS pitch (shorts) for transposed weight rows
#define SLOT  (B_ * H_)   // 16384 shorts = 32 KB per h snapshot
#define DSL   8           // per-team h ring depth (skew <= 1 step, 8 is ample)
#define TSTR  (DSL * SLOT)

typedef __attribute__((ext_vector_type(8))) short short8;   // 8 x bf16
typedef __attribute__((ext_vector_type(4))) float floatx4;

static __device__ __forceinline__ short bf16s(float f) {
    return __builtin_bit_cast(short, __float2bfloat16(f));
}
__device__ __forceinline__ float sigmoidf_(float x) {
    return 1.0f / (1.0f + __expf(-x));
}

// ---- scope-tagged global ops ----
// AGENT=false : sc0 only  -> bypass L1, coherent through the XCD-shared L2 (intra-XCD teams)
// AGENT=true  : sc0 sc1   -> through the L3/coherence point (cross-XCD fallback)
template<bool A>
__device__ __forceinline__ short8 ldg16(const unsigned short* p) {
    short8 v;
    if (A) asm volatile("global_load_dwordx4 %0, %1, off sc0 sc1" : "=v"(v) : "v"(p) : "memory");
    else   asm volatile("global_load_dwordx4 %0, %1, off sc0"     : "=v"(v) : "v"(p) : "memory");
    return v;
}
template<bool A>
__device__ __forceinline__ void stg16(unsigned short* p, short8 v) {
    if (A) asm volatile("global_store_dwordx4 %0, %1, off sc0 sc1" :: "v"(p), "v"(v) : "memory");
    else   asm volatile("global_store_dwordx4 %0, %1, off sc0"     :: "v"(p), "v"(v) : "memory");
}
template<bool A>
__device__ __forceinline__ unsigned ldg4(const unsigned int* p) {
    unsigned v;
    if (A) asm volatile("global_load_dword %0, %1, off sc0 sc1\ns_waitcnt vmcnt(0)" : "=v"(v) : "v"(p) : "memory");
    else   asm volatile("global_load_dword %0, %1, off sc0\ns_waitcnt vmcnt(0)"     : "=v"(v) : "v"(p) : "memory");
    return v;
}
template<bool A>
__device__ __forceinline__ void stg4(unsigned int* p, unsigned v) {
    if (A) asm volatile("global_store_dword %0, %1, off sc0 sc1" :: "v"(p), "v"(v) : "memory");
    else   asm volatile("global_store_dword %0, %1, off sc0"     :: "v"(p), "v"(v) : "memory");
}

// ---------------- prep: x fp32 -> bf16, h0 -> every team's slot (DSL-1) ----------------
__global__ void prep_kernel(const float* __restrict__ x,
                            const float* __restrict__ h0,
                            unsigned short* __restrict__ xb,
                            unsigned short* __restrict__ hbuf,
                            int do_x)
{
    const int tid = threadIdx.x;
    if (blockIdx.x < NTEAM * 64) {
        const int team = blockIdx.x >> 6;
        const int idx  = (blockIdx.x & 63) * 256 + tid;      // 0..16383
        hbuf[(size_t)team * TSTR + (DSL - 1) * SLOT + idx] = (unsigned short)bf16s(h0[idx]);
        return;
    }
    if (!do_x) return;
    const long long base = ((long long)(blockIdx.x - NTEAM * 64) * 256 + tid) * 8;
    const floatx4 a = *(const floatx4*)(x + base);
    const floatx4 b = *(const floatx4*)(x + base + 4);
    short8 s;
    s[0] = bf16s(a[0]); s[1] = bf16s(a[1]); s[2] = bf16s(a[2]); s[3] = bf16s(a[3]);
    s[4] = bf16s(b[0]); s[5] = bf16s(b[1]); s[6] = bf16s(b[2]); s[7] = bf16s(b[3]);
    *(short8*)(xb + base) = s;
}

// ---------------- recurrent core (shared by intra-XCD and agent-fallback modes) ----------------
template<bool AGENT, bool XB>
__device__ __forceinline__ void lstm_core(
    const float* __restrict__ x, const unsigned short* __restrict__ xb,
    const float* __restrict__ c0, const float* __restrict__ bias,
    float* __restrict__ out,
    unsigned short* hbt, unsigned int* flg,
    const int role, const int wys,
    short (*wtI)[WPITCH], short (*wtH)[WPITCH],
    float (*zb)[B_][NCOLS + 2],
    unsigned short (*h_lds)[HCW])
{
    const int tid = threadIdx.x;

    // gate-thread state: 2 cells (b, hc) and (b, hc+8) per thread
    const int gb = tid >> 3, hc = tid & 7;
    const int hg0 = role * HCW + hc, hg1 = hg0 + 8;
    float cv0 = c0[gb * H_ + hg0];
    float cv1 = c0[gb * H_ + hg1];
    float hl0 = 0.f, hl1 = 0.f;
    const float bi0 = bias[0*H_+hg0], bf0 = bias[1*H_+hg0], bg0 = bias[2*H_+hg0], bo0 = bias[3*H_+hg0];
    const float bi1 = bias[0*H_+hg1], bf1 = bias[1*H_+hg1], bg1 = bias[2*H_+hg1], bo1 = bias[3*H_+hg1];

    // wave tiling: wave w -> row-tile mt = w&1, K-half kh = w>>1 (split-K halves L2 h-traffic)
    const int wid = tid >> 6, lane = tid & 63;
    const int mt = wid & 1, kh = wid >> 1;
    const int ln = lane & 15, lq = lane >> 4;
    const int arow = mt * 16 + ln;
    const int kbase = kh * 256;

    float* ys = out + 2 * B_ * H_;

    for (int t = 0; t < T_; ++t) {
        // ---- x-part first: independent of recurrence, overlaps the handoff latency ----
        floatx4 accx[4] = {{0.f,0.f,0.f,0.f},{0.f,0.f,0.f,0.f},{0.f,0.f,0.f,0.f},{0.f,0.f,0.f,0.f}};
        if (XB) {
            const unsigned short* xrow = xb + (size_t)(arow * T_ + t) * F_ + kbase;
            #pragma unroll
            for (int ks = 0; ks < 8; ++ks) {
                const int ko = ks * 32 + lq * 8;
                const short8 ax = *(const short8*)(xrow + ko);
                #pragma unroll
                for (int nt = 0; nt < 4; ++nt) {
                    const short8 bx = *(const short8*)&wtI[nt * 16 + ln][kbase + ko];
                    accx[nt] = __builtin_amdgcn_mfma_f32_16x16x32_bf16(ax, bx, accx[nt], 0, 0, 0);
                }
            }
        } else {
            const float* xrow = x + (size_t)(arow * T_ + t) * F_ + kbase;
            #pragma unroll
            for (int ks = 0; ks < 8; ++ks) {
                const int ko = ks * 32 + lq * 8;
                const floatx4 xa = *(const floatx4*)(xrow + ko);
                const floatx4 xc = *(const floatx4*)(xrow + ko + 4);
                short8 ax;
                ax[0] = bf16s(xa[0]); ax[1] = bf16s(xa[1]); ax[2] = bf16s(xa[2]); ax[3] = bf16s(xa[3]);
                ax[4] = bf16s(xc[0]); ax[5] = bf16s(xc[1]); ax[6] = bf16s(xc[2]); ax[7] = bf16s(xc[3]);
                #pragma unroll
                for (int nt = 0; nt < 4; ++nt) {
                    const short8 bx = *(const short8*)&wtI[nt * 16 + ln][kbase + ko];
                    accx[nt] = __builtin_amdgcn_mfma_f32_16x16x32_bf16(ax, bx, accx[nt], 0, 0, 0);
                }
            }
        }

        // ---- wait for h_{t-1}: wave0 spins on the 32 team flags ----
        if (t > 0) {
            if (wid == 0) {
                int spins = 0;
                while (true) {
                    const unsigned f = ldg4<AGENT>(&flg[lane & (NROLE - 1)]);
                    if (__all((int)(f >= (unsigned)t))) break;
                    if (++spins > (1 << 20)) break;   // deadlock failsafe
                }
            }
            __syncthreads();
        }

        // ---- h-part: 8 scope-tagged 16B loads, single wait, then MFMA (rule #18 fence) ----
        const unsigned short* hrow = hbt + ((t - 1) & (DSL - 1)) * SLOT + arow * H_ + kbase;
        short8 ah[8];
        #pragma unroll
        for (int ks = 0; ks < 8; ++ks)
            ah[ks] = ldg16<AGENT>(hrow + ks * 32 + lq * 8);
        asm volatile("s_waitcnt vmcnt(0)" ::: "memory");
        __builtin_amdgcn_sched_barrier(0);

        floatx4 acch[4] = {{0.f,0.f,0.f,0.f},{0.f,0.f,0.f,0.f},{0.f,0.f,0.f,0.f},{0.f,0.f,0.f,0.f}};
        #pragma unroll
        for (int ks = 0; ks < 8; ++ks) {
            const int ko = kbase + ks * 32 + lq * 8;
            #pragma unroll
            for (int nt = 0; nt < 4; ++nt) {
                const short8 bh = *(const short8*)&wtH[nt * 16 + ln][ko];
                acch[nt] = __builtin_amdgcn_mfma_f32_16x16x32_bf16(ah[ks], bh, acch[nt], 0, 0, 0);
            }
        }
        // C/D layout: col = lane&15, row = (lane>>4)*4 + reg  [m89-verified]
        {
            const int zrow = mt * 16 + lq * 4;
            #pragma unroll
            for (int nt = 0; nt < 4; ++nt) {
                const int zcol = nt * 16 + ln;
                #pragma unroll
                for (int r = 0; r < 4; ++r)
                    zb[kh][zrow + r][zcol] = accx[nt][r] + acch[nt][r];
            }
        }
        __syncthreads();

        // ---- gates: z = zb[kh=0] + zb[kh=1] + bias; local col = gate*16 + u ----
        {
            const float zi0 = zb[0][gb][hc]      + zb[1][gb][hc]      + bi0;
            const float zf0 = zb[0][gb][16 + hc] + zb[1][gb][16 + hc] + bf0;
            const float zg0 = zb[0][gb][32 + hc] + zb[1][gb][32 + hc] + bg0;
            const float zo0 = zb[0][gb][48 + hc] + zb[1][gb][48 + hc] + bo0;
            const float i0 = sigmoidf_(zi0), f0 = sigmoidf_(zf0);
            const float g0 = tanhf(zg0),     o0 = sigmoidf_(zo0);
            cv0 = f0 * cv0 + i0 * g0;
            hl0 = o0 * tanhf(cv0);
            h_lds[gb][hc] = (unsigned short)bf16s(hl0);

            const int h1 = hc + 8;
            const float zi1 = zb[0][gb][h1]      + zb[1][gb][h1]      + bi1;
            const float zf1 = zb[0][gb][16 + h1] + zb[1][gb][16 + h1] + bf1;
            const float zg1 = zb[0][gb][32 + h1] + zb[1][gb][32 + h1] + bg1;
            const float zo1 = zb[0][gb][48 + h1] + zb[1][gb][48 + h1] + bo1;
            const float i1 = sigmoidf_(zi1), f1 = sigmoidf_(zf1);
            const float g1 = tanhf(zg1),     o1 = sigmoidf_(zo1);
            cv1 = f1 * cv1 + i1 * g1;
            hl1 = o1 * tanhf(cv1);
            h_lds[gb][h1] = (unsigned short)bf16s(hl1);

            if (wys) {
                ys[(size_t)(gb * T_ + t) * H_ + hg0] = hl0;
                ys[(size_t)(gb * T_ + t) * H_ + hg1] = hl1;
            }
        }
        __syncthreads();   // h_lds complete before wave0 reads it

        // ---- publish h-slice (1 KB) + flag; other waves already run t+1's x-part.
        //      wave0's h_lds read is ordered vs next gate-writes by the barrier chain. ----
        if (tid < 64) {
            const int row = tid >> 1, c8 = (tid & 1) * 8;
            const short8 v = *(const short8*)&h_lds[row][c8];
            stg16<AGENT>(hbt + (t & (DSL - 1)) * SLOT + row * H_ + role * HCW + c8, v);
            asm volatile("s_waitcnt vmcnt(0)" ::: "memory");   // stores ack'd at coherence point
            if (tid == 0) stg4<AGENT>(&flg[role], (unsigned)(t + 1));
        }
    }

    if (wys) {
        out[gb * H_ + hg0] = cv0;
        out[gb * H_ + hg1] = cv1;
        out[B_ * H_ + gb * H_ + hg0] = hl0;
        out[B_ * H_ + gb * H_ + hg1] = hl1;
    }
}

// ---------------- persistent kernel: team formation + weights + core ----------------
template<bool XB>
__global__ __launch_bounds__(256, 1)
void lstm_loop(const float* __restrict__ x,
               const unsigned short* __restrict__ xb,
               const float* __restrict__ c0,
               const float* __restrict__ Wi,
               const float* __restrict__ Wh,
               const float* __restrict__ bias,
               float* __restrict__ out,
               unsigned short* __restrict__ hbuf,
               unsigned int* __restrict__ ctl)
{
    // 151 KB LDS -> exactly 1 WG/CU -> cooperative 256 WGs means 32 WGs on each XCD.
    __shared__ short wtI[NCOLS][WPITCH];
    __shared__ short wtH[NCOLS][WPITCH];
    __shared__ float zb[2][B_][NCOLS + 2];
    __shared__ __align__(16) unsigned short h_lds[B_][HCW];
    __shared__ int s_role, s_team, s_mode, s_wys;

    const int tid = threadIdx.x;

    if (tid == 0) {
        int xcd;
        asm volatile("s_getreg_b32 %0, hwreg(HW_REG_XCC_ID)" : "=s"(xcd));
        xcd &= (NTEAM - 1);
        const unsigned role  = __hip_atomic_fetch_add(&ctl[xcd], 1u, __ATOMIC_ACQ_REL, __HIP_MEMORY_SCOPE_AGENT);
        const unsigned grank = __hip_atomic_fetch_add(&ctl[8],   1u, __ATOMIC_ACQ_REL, __HIP_MEMORY_SCOPE_AGENT);
        // all 256 WGs register (cooperative => all resident, no deadlock)
        while (__hip_atomic_load(&ctl[8], __ATOMIC_ACQUIRE, __HIP_MEMORY_SCOPE_AGENT)
               < (unsigned)(NTEAM * NROLE)) {}
        // deterministic global agreement on team balance
        int ok = 1;
        for (int i = 0; i < NTEAM; ++i)
            ok &= (__hip_atomic_load(&ctl[i], __ATOMIC_ACQUIRE, __HIP_MEMORY_SCOPE_AGENT)
                   == (unsigned)NROLE);
        s_mode = ok;
        s_team = ok ? xcd : 0;
        s_role = ok ? (int)role : (int)(grank & (NROLE - 1));
        s_wys  = ok ? (xcd == 0) : (grank < (unsigned)NROLE);
    }
    __syncthreads();
    const int mode = s_mode, role = s_role, team = s_team, wys = s_wys;

    // transposed bf16 weight slices: local col j = gate(j>>4)*16 + u(j&15)
    for (int idx = tid; idx < NCOLS * F_; idx += 256) {
        const int j = idx & (NCOLS - 1);
        const int k = idx >> 6;
        const int gcol = (j >> 4) * H_ + role * HCW + (j & 15);
        wtI[j][k] = bf16s(Wi[k * (4 * H_) + gcol]);
        wtH[j][k] = bf16s(Wh[k * (4 * H_) + gcol]);
    }
    __syncthreads();

    unsigned short* hbt = hbuf + (size_t)team * TSTR;
    unsigned int*   flg = ctl + 256 + team * NROLE;

    if (mode) lstm_core<false, XB>(x, xb, c0, bias, out, hbt, flg, role, wys, wtI, wtH, zb, h_lds);
    else      lstm_core<true , XB>(x, xb, c0, bias, out, hbt, flg, role, wys, wtI, wtH, zb, h_lds);
}

extern "C" void kernel_launch(void* const* d_in, const int* in_sizes, int n_in,
                              void* d_out, int out_size, void* d_ws, size_t ws_size,
                              hipStream_t stream) {
    const float* x  = (const float*)d_in[0];
    const float* c0 = (const float*)d_in[1];
    const float* h0 = (const float*)d_in[2];
    const float* Wi = (const float*)d_in[3];
    const float* Wh = (const float*)d_in[4];
    const float* b  = (const float*)d_in[5];
    float* out = (float*)d_out;

    unsigned char* ws = (unsigned char*)d_ws;
    unsigned int*   ctl  = (unsigned int*)ws;                          // [0, 4KB): counters + flags
    unsigned short* hbuf = (unsigned short*)(ws + 65536);              // 8 teams * 256 KB = 2 MB
    unsigned short* xb   = (unsigned short*)(ws + 65536 + (size_t)NTEAM * TSTR * 2);

    const size_t need_xb = 65536 + (size_t)NTEAM * TSTR * 2 + (size_t)B_ * T_ * F_ * 2;
    const int use_xb = (ws_size >= need_xb) ? 1 : 0;

    // ws poisoned before every timed launch: zero the control region
    hipMemsetAsync(ws, 0, 4096, stream);

    const int prep_blocks = NTEAM * 64 + (use_xb ? (B_ * T_ * F_ / 8 / 256) : 0);
    prep_kernel<<<prep_blocks, 256, 0, stream>>>(x, h0, xb, hbuf, use_xb);

    void* args[] = { &x, &xb, &c0, &Wi, &Wh, &b, &out, &hbuf, &ctl };
    hipLaunchCooperativeKernel(use_xb ? (void*)lstm_loop<true> : (void*)lstm_loop<false>,
                               dim3(NTEAM * NROLE), dim3(256), args, 0, stream);
}